// Round 4
// baseline (847.918 us; speedup 1.0000x reference)
//
#include <hip/hip_runtime.h>
#include <stdint.h>

#define T_DIM 512
#define B_DIM 256
#define OBS_DIM 128
#define H_DIM 256
#define TB (T_DIM * B_DIM)

typedef _Float16 f16;
typedef __attribute__((ext_vector_type(8))) _Float16 f16x8;
typedef __attribute__((ext_vector_type(4))) float f32x4;

union H2U { f16 h[2]; uint32_t u; };

__device__ __forceinline__ f32x4 fz4() { f32x4 v; v[0]=0.f; v[1]=0.f; v[2]=0.f; v[3]=0.f; return v; }
__device__ __forceinline__ float sigm(float x) {
  float e = __expf(-x);
  return __builtin_amdgcn_rcpf(1.f + e);
}
__device__ __forceinline__ float tanh_f(float x) {
  float e = __expf(-2.f * x);
  return (1.f - e) * __builtin_amdgcn_rcpf(1.f + e);
}

// ---------------------------------------------------------------------------
// K0: weights -> f16. encW 32768 | Wih 196608 | head 8192 (rows0-15 pol,16 val)
// ---------------------------------------------------------------------------
__global__ void k_prep(const float* __restrict__ encW, const float* __restrict__ Wih,
                       const float* __restrict__ polW, const float* __restrict__ valW,
                       f16* __restrict__ encW_h, f16* __restrict__ Wih_h,
                       f16* __restrict__ headW_h) {
  int e = blockIdx.x * 256 + threadIdx.x;
  if (e < 32768) { encW_h[e] = (f16)encW[e]; return; }
  e -= 32768;
  if (e < 196608) { Wih_h[e] = (f16)Wih[e]; return; }
  e -= 196608;
  if (e < 8192) {
    int r = e >> 8, c = e & 255;
    float v = (r < 16) ? polW[r * 256 + c] : (r == 16 ? valW[c] : 0.f);
    headW_h[e] = (f16)v;
  }
}

// ---------------------------------------------------------------------------
// K1: x = tanh(obs @ enc_W^T + enc_b) -> f16 into xgi. M-tile 128, grid 1024.
// ---------------------------------------------------------------------------
__global__ __launch_bounds__(512) void k_enc(const float* __restrict__ obs,
                                             const f16* __restrict__ encW_h,
                                             const float* __restrict__ enc_b,
                                             f16* __restrict__ xgi) {
  __shared__ f16 lA[128 * 64];  // 16KB [128 rows][64 k] swizzled
  __shared__ f16 lB[256 * 64];  // 32KB [256 n][64 k] swizzled
  const int tid = threadIdx.x, lane = tid & 63, w = tid >> 6;
  const int m0 = blockIdx.x * 128;
  f32x4 acc[16];
#pragma unroll
  for (int i = 0; i < 16; i++) acc[i] = fz4();

  for (int kc = 0; kc < 2; kc++) {
    const int k0c = kc * 64;
#pragma unroll
    for (int i = 0; i < 4; i++) {
      int c = tid + i * 512;
      int r = c >> 4, kk = (c & 15) * 4;
      float4 v = *(const float4*)(obs + (size_t)(m0 + r) * OBS_DIM + k0c + kk);
      H2U a, b;
      a.h[0] = (f16)v.x; a.h[1] = (f16)v.y; b.h[0] = (f16)v.z; b.h[1] = (f16)v.w;
      uint32_t off = ((uint32_t)(r * 128 + kk * 2)) ^ (((uint32_t)(r & 7)) << 4);
      uint2 p; p.x = a.u; p.y = b.u;
      *(uint2*)((char*)lA + off) = p;
    }
#pragma unroll
    for (int i = 0; i < 4; i++) {
      int c = tid + i * 512;
      int r = c >> 3, kk = (c & 7) * 8;
      f16x8 v = *(const f16x8*)(encW_h + (size_t)r * OBS_DIM + k0c + kk);
      uint32_t off = ((uint32_t)(r * 128 + kk * 2)) ^ (((uint32_t)(r & 7)) << 4);
      *(f16x8*)((char*)lB + off) = v;
    }
    __syncthreads();
#pragma unroll
    for (int ks = 0; ks < 2; ks++) {
      const int ar = w * 16 + (lane & 15);
      const int kofs = (ks * 32 + ((lane >> 4) << 3)) * 2;
      uint32_t aoff = ((uint32_t)(ar * 128 + kofs)) ^ (((uint32_t)(ar & 7)) << 4);
      f16x8 af = *(const f16x8*)((char*)lA + aoff);
#pragma unroll
      for (int i = 0; i < 16; i++) {
        const int br = i * 16 + (lane & 15);
        uint32_t boff = ((uint32_t)(br * 128 + kofs)) ^ (((uint32_t)(br & 7)) << 4);
        f16x8 bfr = *(const f16x8*)((char*)lB + boff);
        acc[i] = __builtin_amdgcn_mfma_f32_16x16x32_f16(af, bfr, acc[i], 0, 0, 0);
      }
    }
    __syncthreads();
  }
  const int mrow = m0 + w * 16 + ((lane >> 4) << 2);
#pragma unroll
  for (int i = 0; i < 16; i++) {
    const int col = i * 16 + (lane & 15);
    const float bb = enc_b[col];
#pragma unroll
    for (int r = 0; r < 4; r++) {
      float s = acc[i][r] + bb;
      xgi[(size_t)(mrow + r) * H_DIM + col] = (f16)tanh_f(s);
    }
  }
}

// ---------------------------------------------------------------------------
// K2: all 3 gates fused: gi = x @ W_ih^T + bias. M-tile 64, N=768, grid 2048.
// bias: b_ih + b_hh for r,z cols (<512); b_ih only for n.
// r,z -> gi_rz f16 [TB][256][2] INTERLEAVED; n -> xgi [TB][256].
// ---------------------------------------------------------------------------
__global__ __launch_bounds__(512) void k_gi3(const f16* __restrict__ xgi_r,
                                             const f16* __restrict__ Wih_h,
                                             const float* __restrict__ b_ih,
                                             const float* __restrict__ b_hh,
                                             f16* __restrict__ gi_rz,
                                             f16* __restrict__ xgi_w) {
  __shared__ f16 lA[64 * 64];    // 8KB
  __shared__ f16 lB[768 * 64];   // 96KB
  const int tid = threadIdx.x, lane = tid & 63, w = tid >> 6;
  const int m0 = blockIdx.x * 64;
  const int mstrip = w >> 1, nh = w & 1;
  f32x4 acc[24];
#pragma unroll
  for (int i = 0; i < 24; i++) acc[i] = fz4();

  for (int kc = 0; kc < 4; kc++) {
    const int k0c = kc * 64;
    {
      int r = tid >> 3, kk = (tid & 7) * 8;
      f16x8 v = *(const f16x8*)(xgi_r + (size_t)(m0 + r) * H_DIM + k0c + kk);
      uint32_t off = ((uint32_t)(r * 128 + kk * 2)) ^ (((uint32_t)(r & 7)) << 4);
      *(f16x8*)((char*)lA + off) = v;
    }
#pragma unroll
    for (int i = 0; i < 12; i++) {
      int c = tid + i * 512;
      int r = c >> 3, kk = (c & 7) * 8;
      f16x8 v = *(const f16x8*)(Wih_h + (size_t)r * H_DIM + k0c + kk);
      uint32_t off = ((uint32_t)(r * 128 + kk * 2)) ^ (((uint32_t)(r & 7)) << 4);
      *(f16x8*)((char*)lB + off) = v;
    }
    __syncthreads();
#pragma unroll
    for (int ks = 0; ks < 2; ks++) {
      const int ar = mstrip * 16 + (lane & 15);
      const int kofs = (ks * 32 + ((lane >> 4) << 3)) * 2;
      uint32_t aoff = ((uint32_t)(ar * 128 + kofs)) ^ (((uint32_t)(ar & 7)) << 4);
      f16x8 af = *(const f16x8*)((char*)lA + aoff);
#pragma unroll
      for (int i = 0; i < 24; i++) {
        const int br = nh * 384 + i * 16 + (lane & 15);
        uint32_t boff = ((uint32_t)(br * 128 + kofs)) ^ (((uint32_t)(br & 7)) << 4);
        f16x8 bfr = *(const f16x8*)((char*)lB + boff);
        acc[i] = __builtin_amdgcn_mfma_f32_16x16x32_f16(af, bfr, acc[i], 0, 0, 0);
      }
    }
    __syncthreads();
  }
  const int mrow = m0 + mstrip * 16 + ((lane >> 4) << 2);
#pragma unroll
  for (int i = 0; i < 24; i++) {
    const int col = nh * 384 + i * 16 + (lane & 15);
    float bb = b_ih[col];
    if (col < 512) bb += b_hh[col];
#pragma unroll
    for (int r = 0; r < 4; r++) {
      float s = acc[i][r] + bb;
      size_t tb = (size_t)(mrow + r);
      if (col < 512) gi_rz[tb * 512 + (size_t)((col & 255) * 2 + (col >> 8))] = (f16)s;
      else           xgi_w[tb * 256 + (col - 512)] = (f16)s;
    }
  }
}

// ---------------------------------------------------------------------------
// K3: GRU scan v4. grid(128) x block 512 (8 waves), WG owns 2 batch rows.
// W_hh: ks 0-5 resident in regs (144 VGPR/lane), ks 6-7 as prebuilt B-frags
// in LDS (96KB, lane-linear) -> total regs ~220 < 256, NO spill.
// gi prefetched one full step ahead in registers. gh redistribution guarded
// by asm lgkmcnt(0) + sched_barrier (no vmcnt drain -> outs store stays
// fire-and-forget). h-prev kept in register. One __syncthreads per step.
// ---------------------------------------------------------------------------
__global__ __launch_bounds__(512) void k_scan(const float* __restrict__ Whh,
                                              const float* __restrict__ b_hh,
                                              const float* __restrict__ done,
                                              const uint32_t* __restrict__ gi_rz,
                                              f16* xgi) {
  __shared__ f16 h_l[2][16][264];      // 16.5KB double-buffered, rows 2-15 stay 0
  __shared__ float gh_l[8][6][16][2];  // 6KB [wave][g*2+hh][col&15][row]
  __shared__ float done_l[T_DIM][2];   // 4KB
  __shared__ f16 wb_l[48 * 2 * 64 * 8];  // 96KB: B-frags for ks 6,7 lane-linear
  const int tid = threadIdx.x, lane = tid & 63, w = tid >> 6;
  const int b0 = blockIdx.x * 2;

  for (int i = tid; i < 2 * 16 * 264; i += 512) ((f16*)h_l)[i] = (f16)0.f;
  {
    float2 dv = *(const float2*)(done + (size_t)tid * B_DIM + b0);
    done_l[tid][0] = dv.x; done_l[tid][1] = dv.y;
  }

  // W_hh -> f16 B-frags: ks 0-5 in registers, ks 6-7 into LDS
  f16x8 wf[6][6];
#pragma unroll
  for (int g = 0; g < 3; g++) {
#pragma unroll
    for (int hh = 0; hh < 2; hh++) {
      const int i6 = g * 2 + hh;
      const int rowW = g * 256 + w * 32 + hh * 16 + (lane & 15);
      const float* wrow = Whh + (size_t)rowW * H_DIM;
#pragma unroll
      for (int ks = 0; ks < 8; ks++) {
        const int k0 = ks * 32 + ((lane >> 4) << 3);
        float4 a = *(const float4*)(wrow + k0);
        float4 b = *(const float4*)(wrow + k0 + 4);
        f16x8 f;
        f[0] = (f16)a.x; f[1] = (f16)a.y; f[2] = (f16)a.z; f[3] = (f16)a.w;
        f[4] = (f16)b.x; f[5] = (f16)b.y; f[6] = (f16)b.z; f[7] = (f16)b.w;
        if (ks < 6) wf[i6][ks] = f;
        else *(f16x8*)&wb_l[(((w * 6 + i6) * 2 + (ks - 6)) * 64 + lane) * 8] = f;
      }
    }
  }
  const int row = lane >> 5, c = lane & 31, col = (w << 5) + c;
  const float bhhn = b_hh[512 + col];

  // prefetch gi for t=0
  uint32_t rz_nx = gi_rz[((size_t)b0 + row) * 256 + col];
  f16 gn_nx = xgi[((size_t)b0 + row) * 256 + col];
  float hreg = 0.f;
  __syncthreads();

  for (int t = 0; t < T_DIM; t++) {
    const int cur = t & 1, nxt = cur ^ 1;
    const uint32_t rz_cu = rz_nx;   // loaded one full step ago
    const f16 gn_cu = gn_nx;
    const int tn = (t + 1 < T_DIM) ? t + 1 : t;
    const size_t tbn = ((size_t)tn * B_DIM + b0 + row) * 256 + col;
    rz_nx = gi_rz[tbn];
    gn_nx = xgi[tbn];

    // phase A: gh = h @ W_hh^T
    f32x4 acc[6];
#pragma unroll
    for (int i = 0; i < 6; i++) acc[i] = fz4();
#pragma unroll
    for (int ks = 0; ks < 6; ks++) {
      const f16x8 af = *(const f16x8*)&h_l[cur][lane & 15][ks * 32 + ((lane >> 4) << 3)];
#pragma unroll
      for (int i = 0; i < 6; i++)
        acc[i] = __builtin_amdgcn_mfma_f32_16x16x32_f16(af, wf[i][ks], acc[i], 0, 0, 0);
    }
#pragma unroll
    for (int j = 0; j < 2; j++) {
      const f16x8 af = *(const f16x8*)&h_l[cur][lane & 15][(6 + j) * 32 + ((lane >> 4) << 3)];
#pragma unroll
      for (int i = 0; i < 6; i++) {
        const f16x8 bf = *(const f16x8*)&wb_l[(((w * 6 + i) * 2 + j) * 64 + lane) * 8];
        acc[i] = __builtin_amdgcn_mfma_f32_16x16x32_f16(af, bf, acc[i], 0, 0, 0);
      }
    }
    // wave-local gh redistribution (lanes 0-15 hold batch rows 0,1 in regs 0,1)
    if (lane < 16) {
#pragma unroll
      for (int i = 0; i < 6; i++) {
        float2 v; v.x = acc[i][0]; v.y = acc[i][1];
        *(float2*)&gh_l[w][i][lane][0] = v;
      }
    }
    __builtin_amdgcn_sched_barrier(0);
    asm volatile("s_waitcnt lgkmcnt(0)" ::: "memory");
    __builtin_amdgcn_sched_barrier(0);
    const int hh = c >> 4, cl = c & 15;
    const float ghr = gh_l[w][0 + hh][cl][row];
    const float ghz = gh_l[w][2 + hh][cl][row];
    const float ghn = gh_l[w][4 + hh][cl][row];
    H2U u; u.u = rz_cu;
    const float gr = (float)u.h[0], gz = (float)u.h[1], gn = (float)gn_cu;
    const float rr = sigm(gr + ghr);
    const float zz = sigm(gz + ghz);
    const float nn = tanh_f(gn + rr * (ghn + bhhn));
    const float ho = nn + zz * (hreg - nn);
    xgi[((size_t)t * B_DIM + b0 + row) * 256 + col] = (f16)ho;  // outs
    const float dn = done_l[t][row];                            // masks into t+1
    hreg = (dn != 0.f) ? 0.f : ho;
    h_l[nxt][row][col] = (f16)hreg;
    __syncthreads();
  }
}

// ---------------------------------------------------------------------------
// K4: heads. M-tile 64, N=32 (16 pol + 1 val + pad), grid 2048, block 256.
// ---------------------------------------------------------------------------
__global__ __launch_bounds__(256) void k_heads(const f16* __restrict__ outs,
                                               const f16* __restrict__ headW_h,
                                               const float* __restrict__ pol_b,
                                               const float* __restrict__ val_b,
                                               float* __restrict__ out) {
  __shared__ f16 lA[64 * 256];  // 32KB swizzled
  __shared__ f16 lB[32 * 256];  // 16KB
  const int tid = threadIdx.x, lane = tid & 63, w = tid >> 6;
  const int m0 = blockIdx.x * 64;
#pragma unroll
  for (int i = 0; i < 8; i++) {
    int c = tid + i * 256;
    int r = c >> 5, o = (c & 31) * 8;
    f16x8 v = *(const f16x8*)(outs + (size_t)(m0 + r) * H_DIM + o);
    uint32_t off = ((uint32_t)(r * 512 + o * 2)) ^ (((uint32_t)(r & 7)) << 4);
    *(f16x8*)((char*)lA + off) = v;
  }
#pragma unroll
  for (int i = 0; i < 4; i++) {
    int c = tid + i * 256;
    int r = c >> 5, o = (c & 31) * 8;
    f16x8 v = *(const f16x8*)(headW_h + (size_t)r * H_DIM + o);
    uint32_t off = ((uint32_t)(r * 512 + o * 2)) ^ (((uint32_t)(r & 7)) << 4);
    *(f16x8*)((char*)lB + off) = v;
  }
  __syncthreads();
  f32x4 acc[2];
  acc[0] = fz4(); acc[1] = fz4();
#pragma unroll
  for (int ks = 0; ks < 8; ks++) {
    const int ar = w * 16 + (lane & 15);
    const int kofs = (ks * 32 + ((lane >> 4) << 3)) * 2;
    uint32_t aoff = ((uint32_t)(ar * 512 + kofs)) ^ (((uint32_t)(ar & 7)) << 4);
    f16x8 af = *(const f16x8*)((char*)lA + aoff);
#pragma unroll
    for (int nt = 0; nt < 2; nt++) {
      const int br = nt * 16 + (lane & 15);
      uint32_t boff = ((uint32_t)(br * 512 + kofs)) ^ (((uint32_t)(br & 7)) << 4);
      f16x8 bfr = *(const f16x8*)((char*)lB + boff);
      acc[nt] = __builtin_amdgcn_mfma_f32_16x16x32_f16(af, bfr, acc[nt], 0, 0, 0);
    }
  }
  const int n = lane & 15;
  const float pb = pol_b[n];
  const float vb = val_b[0];
#pragma unroll
  for (int r = 0; r < 4; r++) {
    const int mrow = m0 + w * 16 + ((lane >> 4) << 2) + r;
    out[(size_t)mrow * 16 + n] = acc[0][r] + pb;
    if (n == 0) out[(size_t)TB * 16 + mrow] = acc[1][r] + vb;
  }
}

// ---------------------------------------------------------------------------
// Workspace layout (192.5 MiB total):
//   [0,128Mi)        gi_rz f16 [TB][256][2]  (r,z interleaved)
//   [128Mi,192Mi)    xgi  f16 [TB][256]  (x -> gi_n -> outs, race-free)
//   [192Mi,+475KB)   encW_h | Wih_h | headW_h
// ---------------------------------------------------------------------------
extern "C" void kernel_launch(void* const* d_in, const int* in_sizes, int n_in,
                              void* d_out, int out_size, void* d_ws, size_t ws_size,
                              hipStream_t stream) {
  (void)in_sizes; (void)n_in; (void)out_size; (void)ws_size;
  const float* obs   = (const float*)d_in[0];
  const float* done  = (const float*)d_in[1];
  const float* encW  = (const float*)d_in[2];
  const float* enc_b = (const float*)d_in[3];
  const float* Wih   = (const float*)d_in[4];
  const float* Whh   = (const float*)d_in[5];
  const float* b_ih  = (const float*)d_in[6];
  const float* b_hh  = (const float*)d_in[7];
  const float* polW  = (const float*)d_in[8];
  const float* pol_b = (const float*)d_in[9];
  const float* valW  = (const float*)d_in[10];
  const float* val_b = (const float*)d_in[11];

  char* ws = (char*)d_ws;
  f16* gi_rz   = (f16*)ws;
  f16* xgi     = (f16*)(ws + (size_t)134217728);
  f16* encW_h  = (f16*)(ws + (size_t)201326592);
  f16* Wih_h   = encW_h + 32768;
  f16* headW_h = Wih_h + 196608;
  float* outp  = (float*)d_out;

  k_prep<<<dim3(928), dim3(256), 0, stream>>>(encW, Wih, polW, valW, encW_h, Wih_h, headW_h);
  k_enc<<<dim3(1024), dim3(512), 0, stream>>>(obs, encW_h, enc_b, xgi);
  k_gi3<<<dim3(2048), dim3(512), 0, stream>>>(xgi, Wih_h, b_ih, b_hh, gi_rz, xgi);
  k_scan<<<dim3(128), dim3(512), 0, stream>>>(Whh, b_hh, done, (const uint32_t*)gi_rz, xgi);
  k_heads<<<dim3(2048), dim3(256), 0, stream>>>(xgi, headW_h, pol_b, val_b, outp);
}

// Round 5
// 831.623 us; speedup vs baseline: 1.0196x; 1.0196x over previous
//
#include <hip/hip_runtime.h>
#include <stdint.h>

#define T_DIM 512
#define B_DIM 256
#define OBS_DIM 128
#define H_DIM 256
#define TB (T_DIM * B_DIM)

typedef _Float16 f16;
typedef __attribute__((ext_vector_type(8))) _Float16 f16x8;
typedef __attribute__((ext_vector_type(4))) float f32x4;

union H2U { f16 h[2]; uint32_t u; };

__device__ __forceinline__ f32x4 fz4() { f32x4 v; v[0]=0.f; v[1]=0.f; v[2]=0.f; v[3]=0.f; return v; }
__device__ __forceinline__ float sigm(float x) {
  float e = __expf(-x);
  return __builtin_amdgcn_rcpf(1.f + e);
}
__device__ __forceinline__ float tanh_f(float x) {
  float e = __expf(-2.f * x);
  return (1.f - e) * __builtin_amdgcn_rcpf(1.f + e);
}

// ---------------------------------------------------------------------------
// K0: weights -> f16. encW 32768 | Wih 196608 | head 8192 (rows0-15 pol,16 val)
// ---------------------------------------------------------------------------
__global__ void k_prep(const float* __restrict__ encW, const float* __restrict__ Wih,
                       const float* __restrict__ polW, const float* __restrict__ valW,
                       f16* __restrict__ encW_h, f16* __restrict__ Wih_h,
                       f16* __restrict__ headW_h) {
  int e = blockIdx.x * 256 + threadIdx.x;
  if (e < 32768) { encW_h[e] = (f16)encW[e]; return; }
  e -= 32768;
  if (e < 196608) { Wih_h[e] = (f16)Wih[e]; return; }
  e -= 196608;
  if (e < 8192) {
    int r = e >> 8, c = e & 255;
    float v = (r < 16) ? polW[r * 256 + c] : (r == 16 ? valW[c] : 0.f);
    headW_h[e] = (f16)v;
  }
}

// ---------------------------------------------------------------------------
// K1: x = tanh(obs @ enc_W^T + enc_b) -> f16 into xgi. M-tile 128, grid 1024.
// ---------------------------------------------------------------------------
__global__ __launch_bounds__(512) void k_enc(const float* __restrict__ obs,
                                             const f16* __restrict__ encW_h,
                                             const float* __restrict__ enc_b,
                                             f16* __restrict__ xgi) {
  __shared__ f16 lA[128 * 64];  // 16KB [128 rows][64 k] swizzled
  __shared__ f16 lB[256 * 64];  // 32KB [256 n][64 k] swizzled
  const int tid = threadIdx.x, lane = tid & 63, w = tid >> 6;
  const int m0 = blockIdx.x * 128;
  f32x4 acc[16];
#pragma unroll
  for (int i = 0; i < 16; i++) acc[i] = fz4();

  for (int kc = 0; kc < 2; kc++) {
    const int k0c = kc * 64;
#pragma unroll
    for (int i = 0; i < 4; i++) {
      int c = tid + i * 512;
      int r = c >> 4, kk = (c & 15) * 4;
      float4 v = *(const float4*)(obs + (size_t)(m0 + r) * OBS_DIM + k0c + kk);
      H2U a, b;
      a.h[0] = (f16)v.x; a.h[1] = (f16)v.y; b.h[0] = (f16)v.z; b.h[1] = (f16)v.w;
      uint32_t off = ((uint32_t)(r * 128 + kk * 2)) ^ (((uint32_t)(r & 7)) << 4);
      uint2 p; p.x = a.u; p.y = b.u;
      *(uint2*)((char*)lA + off) = p;
    }
#pragma unroll
    for (int i = 0; i < 4; i++) {
      int c = tid + i * 512;
      int r = c >> 3, kk = (c & 7) * 8;
      f16x8 v = *(const f16x8*)(encW_h + (size_t)r * OBS_DIM + k0c + kk);
      uint32_t off = ((uint32_t)(r * 128 + kk * 2)) ^ (((uint32_t)(r & 7)) << 4);
      *(f16x8*)((char*)lB + off) = v;
    }
    __syncthreads();
#pragma unroll
    for (int ks = 0; ks < 2; ks++) {
      const int ar = w * 16 + (lane & 15);
      const int kofs = (ks * 32 + ((lane >> 4) << 3)) * 2;
      uint32_t aoff = ((uint32_t)(ar * 128 + kofs)) ^ (((uint32_t)(ar & 7)) << 4);
      f16x8 af = *(const f16x8*)((char*)lA + aoff);
#pragma unroll
      for (int i = 0; i < 16; i++) {
        const int br = i * 16 + (lane & 15);
        uint32_t boff = ((uint32_t)(br * 128 + kofs)) ^ (((uint32_t)(br & 7)) << 4);
        f16x8 bfr = *(const f16x8*)((char*)lB + boff);
        acc[i] = __builtin_amdgcn_mfma_f32_16x16x32_f16(af, bfr, acc[i], 0, 0, 0);
      }
    }
    __syncthreads();
  }
  const int mrow = m0 + w * 16 + ((lane >> 4) << 2);
#pragma unroll
  for (int i = 0; i < 16; i++) {
    const int col = i * 16 + (lane & 15);
    const float bb = enc_b[col];
#pragma unroll
    for (int r = 0; r < 4; r++) {
      float s = acc[i][r] + bb;
      xgi[(size_t)(mrow + r) * H_DIM + col] = (f16)tanh_f(s);
    }
  }
}

// ---------------------------------------------------------------------------
// K2: all 3 gates fused: gi = x @ W_ih^T + bias. M-tile 64, N=768, grid 2048.
// bias: b_ih + b_hh for r,z cols (<512); b_ih only for n.
// r,z -> gi_rz f16 [TB][256][2] INTERLEAVED; n -> xgi [TB][256].
// ---------------------------------------------------------------------------
__global__ __launch_bounds__(512) void k_gi3(const f16* __restrict__ xgi_r,
                                             const f16* __restrict__ Wih_h,
                                             const float* __restrict__ b_ih,
                                             const float* __restrict__ b_hh,
                                             f16* __restrict__ gi_rz,
                                             f16* __restrict__ xgi_w) {
  __shared__ f16 lA[64 * 64];    // 8KB
  __shared__ f16 lB[768 * 64];   // 96KB
  const int tid = threadIdx.x, lane = tid & 63, w = tid >> 6;
  const int m0 = blockIdx.x * 64;
  const int mstrip = w >> 1, nh = w & 1;
  f32x4 acc[24];
#pragma unroll
  for (int i = 0; i < 24; i++) acc[i] = fz4();

  for (int kc = 0; kc < 4; kc++) {
    const int k0c = kc * 64;
    {
      int r = tid >> 3, kk = (tid & 7) * 8;
      f16x8 v = *(const f16x8*)(xgi_r + (size_t)(m0 + r) * H_DIM + k0c + kk);
      uint32_t off = ((uint32_t)(r * 128 + kk * 2)) ^ (((uint32_t)(r & 7)) << 4);
      *(f16x8*)((char*)lA + off) = v;
    }
#pragma unroll
    for (int i = 0; i < 12; i++) {
      int c = tid + i * 512;
      int r = c >> 3, kk = (c & 7) * 8;
      f16x8 v = *(const f16x8*)(Wih_h + (size_t)r * H_DIM + k0c + kk);
      uint32_t off = ((uint32_t)(r * 128 + kk * 2)) ^ (((uint32_t)(r & 7)) << 4);
      *(f16x8*)((char*)lB + off) = v;
    }
    __syncthreads();
#pragma unroll
    for (int ks = 0; ks < 2; ks++) {
      const int ar = mstrip * 16 + (lane & 15);
      const int kofs = (ks * 32 + ((lane >> 4) << 3)) * 2;
      uint32_t aoff = ((uint32_t)(ar * 128 + kofs)) ^ (((uint32_t)(ar & 7)) << 4);
      f16x8 af = *(const f16x8*)((char*)lA + aoff);
#pragma unroll
      for (int i = 0; i < 24; i++) {
        const int br = nh * 384 + i * 16 + (lane & 15);
        uint32_t boff = ((uint32_t)(br * 128 + kofs)) ^ (((uint32_t)(br & 7)) << 4);
        f16x8 bfr = *(const f16x8*)((char*)lB + boff);
        acc[i] = __builtin_amdgcn_mfma_f32_16x16x32_f16(af, bfr, acc[i], 0, 0, 0);
      }
    }
    __syncthreads();
  }
  const int mrow = m0 + mstrip * 16 + ((lane >> 4) << 2);
#pragma unroll
  for (int i = 0; i < 24; i++) {
    const int col = nh * 384 + i * 16 + (lane & 15);
    float bb = b_ih[col];
    if (col < 512) bb += b_hh[col];
#pragma unroll
    for (int r = 0; r < 4; r++) {
      float s = acc[i][r] + bb;
      size_t tb = (size_t)(mrow + r);
      if (col < 512) gi_rz[tb * 512 + (size_t)((col & 255) * 2 + (col >> 8))] = (f16)s;
      else           xgi_w[tb * 256 + (col - 512)] = (f16)s;
    }
  }
}

// ---------------------------------------------------------------------------
// K3: GRU scan v5. grid(128) x block 512 (8 waves), WG owns 2 batch rows.
// Changes vs v4 (all overhead-shaving, structure identical):
//  - MFMA C-in seeded from persistent vectors (zero / bhh_n) -> no per-step
//    acc zero-init movs, bhhn add folded into the matmul.
//  - gi / outs addresses are incremented pointers (no per-step 64b math).
//  - wb_l relayout: per-wave frags contiguous -> ONE vaddr + imm offsets.
//  - h_l / gh_l reads via per-lane base + imm offsets.
//  - s_setprio(1) around the MFMA cluster; __launch_bounds__(512,2).
// ---------------------------------------------------------------------------
__global__ __launch_bounds__(512, 2) void k_scan(const float* __restrict__ Whh,
                                                 const float* __restrict__ b_hh,
                                                 const float* __restrict__ done,
                                                 const uint32_t* __restrict__ gi_rz,
                                                 f16* xgi) {
  __shared__ f16 h_l[2][16][264];      // 16.5KB double-buffered, rows 2-15 stay 0
  __shared__ float gh_l[8][6][16][2];  // 6KB [wave][g*2+hh][col&15][row]
  __shared__ float done_l[T_DIM][2];   // 4KB
  __shared__ f16 wb_l[8 * 12 * 64 * 8];  // 96KB [w][i2j][lane][8] ks 6,7 frags
  const int tid = threadIdx.x, lane = tid & 63, w = tid >> 6;
  const int b0 = blockIdx.x * 2;

  for (int i = tid; i < 2 * 16 * 264; i += 512) ((f16*)h_l)[i] = (f16)0.f;
  {
    float2 dv = *(const float2*)(done + (size_t)tid * B_DIM + b0);
    done_l[tid][0] = dv.x; done_l[tid][1] = dv.y;
  }

  // W_hh -> f16 B-frags: ks 0-5 in registers, ks 6-7 into LDS (lane-contig)
  f16x8 wf[6][6];
#pragma unroll
  for (int g = 0; g < 3; g++) {
#pragma unroll
    for (int hh = 0; hh < 2; hh++) {
      const int i6 = g * 2 + hh;
      const int rowW = g * 256 + w * 32 + hh * 16 + (lane & 15);
      const float* wrow = Whh + (size_t)rowW * H_DIM;
#pragma unroll
      for (int ks = 0; ks < 8; ks++) {
        const int k0 = ks * 32 + ((lane >> 4) << 3);
        float4 a = *(const float4*)(wrow + k0);
        float4 b = *(const float4*)(wrow + k0 + 4);
        f16x8 f;
        f[0] = (f16)a.x; f[1] = (f16)a.y; f[2] = (f16)a.z; f[3] = (f16)a.w;
        f[4] = (f16)b.x; f[5] = (f16)b.y; f[6] = (f16)b.z; f[7] = (f16)b.w;
        if (ks < 6) wf[i6][ks] = f;
        else *(f16x8*)&wb_l[((w * 12 + i6 * 2 + (ks - 6)) * 64 + lane) * 8] = f;
      }
    }
  }
  // persistent C-in seeds: zero for r,z (bias folded in gi); bhh_n for n gate
  f32x4 zs = fz4();
  f32x4 ns0, ns1;
  {
    const float bv0 = b_hh[512 + w * 32 + (lane & 15)];
    const float bv1 = b_hh[512 + w * 32 + 16 + (lane & 15)];
    ns0[0] = bv0; ns0[1] = bv0; ns0[2] = bv0; ns0[3] = bv0;
    ns1[0] = bv1; ns1[1] = bv1; ns1[2] = bv1; ns1[3] = bv1;
  }

  const int row = lane >> 5, c = lane & 31, col = (w << 5) + c;
  const size_t base = ((size_t)b0 + row) * 256 + col;
  const uint32_t* prz = gi_rz + base;
  const f16* pgn = xgi + base;
  f16* pst = xgi + base;
  uint32_t rz_nx = *prz;
  f16 gn_nx = *pgn;
  float hreg = 0.f;

  const f16* hrd0 = &h_l[0][lane & 15][(lane >> 4) << 3];
  const f16* wrd = &wb_l[(w * 12 * 64 + lane) * 8];
  __syncthreads();

  for (int t = 0; t < T_DIM; t++) {
    const uint32_t rz_cu = rz_nx;
    const f16 gn_cu = gn_nx;
    if (t != T_DIM - 1) { prz += 65536; pgn += 65536; rz_nx = *prz; gn_nx = *pgn; }
    const int cur = t & 1;
    const f16* hrd = hrd0 + cur * (16 * 264);

    f32x4 acc[6];
    __builtin_amdgcn_s_setprio(1);
    {
      const f16x8 af0 = *(const f16x8*)&hrd[0];
      acc[0] = __builtin_amdgcn_mfma_f32_16x16x32_f16(af0, wf[0][0], zs, 0, 0, 0);
      acc[1] = __builtin_amdgcn_mfma_f32_16x16x32_f16(af0, wf[1][0], zs, 0, 0, 0);
      acc[2] = __builtin_amdgcn_mfma_f32_16x16x32_f16(af0, wf[2][0], zs, 0, 0, 0);
      acc[3] = __builtin_amdgcn_mfma_f32_16x16x32_f16(af0, wf[3][0], zs, 0, 0, 0);
      acc[4] = __builtin_amdgcn_mfma_f32_16x16x32_f16(af0, wf[4][0], ns0, 0, 0, 0);
      acc[5] = __builtin_amdgcn_mfma_f32_16x16x32_f16(af0, wf[5][0], ns1, 0, 0, 0);
    }
#pragma unroll
    for (int ks = 1; ks < 6; ks++) {
      const f16x8 af = *(const f16x8*)&hrd[ks * 32];
#pragma unroll
      for (int i = 0; i < 6; i++)
        acc[i] = __builtin_amdgcn_mfma_f32_16x16x32_f16(af, wf[i][ks], acc[i], 0, 0, 0);
    }
#pragma unroll
    for (int j = 0; j < 2; j++) {
      const f16x8 af = *(const f16x8*)&hrd[(6 + j) * 32];
#pragma unroll
      for (int i = 0; i < 6; i++) {
        const f16x8 bf = *(const f16x8*)&wrd[(i * 2 + j) * 512];
        acc[i] = __builtin_amdgcn_mfma_f32_16x16x32_f16(af, bf, acc[i], 0, 0, 0);
      }
    }
    __builtin_amdgcn_s_setprio(0);

    // wave-local gh redistribution (lanes 0-15 hold batch rows 0,1 in regs 0,1)
    if (lane < 16) {
#pragma unroll
      for (int i = 0; i < 6; i++) {
        float2 v; v.x = acc[i][0]; v.y = acc[i][1];
        *(float2*)&gh_l[w][i][lane][0] = v;
      }
    }
    __builtin_amdgcn_sched_barrier(0);
    asm volatile("s_waitcnt lgkmcnt(0)" ::: "memory");
    __builtin_amdgcn_sched_barrier(0);
    const int hh = c >> 4, cl = c & 15;
    const float ghr = gh_l[w][0 + hh][cl][row];
    const float ghz = gh_l[w][2 + hh][cl][row];
    const float ghn = gh_l[w][4 + hh][cl][row];
    H2U u; u.u = rz_cu;
    const float rr = sigm((float)u.h[0] + ghr);
    const float zz = sigm((float)u.h[1] + ghz);
    const float nn = tanh_f((float)gn_cu + rr * ghn);
    const float ho = nn + zz * (hreg - nn);
    *pst = (f16)ho; pst += 65536;                 // outs (same addr as gn slot)
    const float dn = done_l[t][row];              // masks h going into t+1
    hreg = (dn != 0.f) ? 0.f : ho;
    h_l[cur ^ 1][row][col] = (f16)hreg;
    __syncthreads();
  }
}

// ---------------------------------------------------------------------------
// K4: heads. M-tile 64, N=32 (16 pol + 1 val + pad), grid 2048, block 256.
// ---------------------------------------------------------------------------
__global__ __launch_bounds__(256) void k_heads(const f16* __restrict__ outs,
                                               const f16* __restrict__ headW_h,
                                               const float* __restrict__ pol_b,
                                               const float* __restrict__ val_b,
                                               float* __restrict__ out) {
  __shared__ f16 lA[64 * 256];  // 32KB swizzled
  __shared__ f16 lB[32 * 256];  // 16KB
  const int tid = threadIdx.x, lane = tid & 63, w = tid >> 6;
  const int m0 = blockIdx.x * 64;
#pragma unroll
  for (int i = 0; i < 8; i++) {
    int c = tid + i * 256;
    int r = c >> 5, o = (c & 31) * 8;
    f16x8 v = *(const f16x8*)(outs + (size_t)(m0 + r) * H_DIM + o);
    uint32_t off = ((uint32_t)(r * 512 + o * 2)) ^ (((uint32_t)(r & 7)) << 4);
    *(f16x8*)((char*)lA + off) = v;
  }
#pragma unroll
  for (int i = 0; i < 4; i++) {
    int c = tid + i * 256;
    int r = c >> 5, o = (c & 31) * 8;
    f16x8 v = *(const f16x8*)(headW_h + (size_t)r * H_DIM + o);
    uint32_t off = ((uint32_t)(r * 512 + o * 2)) ^ (((uint32_t)(r & 7)) << 4);
    *(f16x8*)((char*)lB + off) = v;
  }
  __syncthreads();
  f32x4 acc[2];
  acc[0] = fz4(); acc[1] = fz4();
#pragma unroll
  for (int ks = 0; ks < 8; ks++) {
    const int ar = w * 16 + (lane & 15);
    const int kofs = (ks * 32 + ((lane >> 4) << 3)) * 2;
    uint32_t aoff = ((uint32_t)(ar * 512 + kofs)) ^ (((uint32_t)(ar & 7)) << 4);
    f16x8 af = *(const f16x8*)((char*)lA + aoff);
#pragma unroll
    for (int nt = 0; nt < 2; nt++) {
      const int br = nt * 16 + (lane & 15);
      uint32_t boff = ((uint32_t)(br * 512 + kofs)) ^ (((uint32_t)(br & 7)) << 4);
      f16x8 bfr = *(const f16x8*)((char*)lB + boff);
      acc[nt] = __builtin_amdgcn_mfma_f32_16x16x32_f16(af, bfr, acc[nt], 0, 0, 0);
    }
  }
  const int n = lane & 15;
  const float pb = pol_b[n];
  const float vb = val_b[0];
#pragma unroll
  for (int r = 0; r < 4; r++) {
    const int mrow = m0 + w * 16 + ((lane >> 4) << 2) + r;
    out[(size_t)mrow * 16 + n] = acc[0][r] + pb;
    if (n == 0) out[(size_t)TB * 16 + mrow] = acc[1][r] + vb;
  }
}

// ---------------------------------------------------------------------------
// Workspace layout (192.5 MiB total):
//   [0,128Mi)        gi_rz f16 [TB][256][2]  (r,z interleaved)
//   [128Mi,192Mi)    xgi  f16 [TB][256]  (x -> gi_n -> outs, race-free)
//   [192Mi,+475KB)   encW_h | Wih_h | headW_h
// ---------------------------------------------------------------------------
extern "C" void kernel_launch(void* const* d_in, const int* in_sizes, int n_in,
                              void* d_out, int out_size, void* d_ws, size_t ws_size,
                              hipStream_t stream) {
  (void)in_sizes; (void)n_in; (void)out_size; (void)ws_size;
  const float* obs   = (const float*)d_in[0];
  const float* done  = (const float*)d_in[1];
  const float* encW  = (const float*)d_in[2];
  const float* enc_b = (const float*)d_in[3];
  const float* Wih   = (const float*)d_in[4];
  const float* Whh   = (const float*)d_in[5];
  const float* b_ih  = (const float*)d_in[6];
  const float* b_hh  = (const float*)d_in[7];
  const float* polW  = (const float*)d_in[8];
  const float* pol_b = (const float*)d_in[9];
  const float* valW  = (const float*)d_in[10];
  const float* val_b = (const float*)d_in[11];

  char* ws = (char*)d_ws;
  f16* gi_rz   = (f16*)ws;
  f16* xgi     = (f16*)(ws + (size_t)134217728);
  f16* encW_h  = (f16*)(ws + (size_t)201326592);
  f16* Wih_h   = encW_h + 32768;
  f16* headW_h = Wih_h + 196608;
  float* outp  = (float*)d_out;

  k_prep<<<dim3(928), dim3(256), 0, stream>>>(encW, Wih, polW, valW, encW_h, Wih_h, headW_h);
  k_enc<<<dim3(1024), dim3(512), 0, stream>>>(obs, encW_h, enc_b, xgi);
  k_gi3<<<dim3(2048), dim3(512), 0, stream>>>(xgi, Wih_h, b_ih, b_hh, gi_rz, xgi);
  k_scan<<<dim3(128), dim3(512), 0, stream>>>(Whh, b_hh, done, (const uint32_t*)gi_rz, xgi);
  k_heads<<<dim3(2048), dim3(256), 0, stream>>>(xgi, headW_h, pol_b, val_b, outp);
}